// Round 7
// baseline (147.421 us; speedup 1.0000x reference)
//
#include <hip/hip_runtime.h>

// SSIM fused, v7: barrier-free MFMA band-matmul conv.
// Key insight: in the v6 layout, the wave that produces H-columns [ct*16..ct*16+15]
// is the SAME wave that consumes them in the v-pass (ct == wave). The LDS round
// trip only redistributes rows within the wave -> needs lgkmcnt (compiler), NOT
// __syncthreads. Each wave gets a private hbuf region and writes its own partial:
// ZERO barriers in the whole kernel. 20 independent waves/CU hide global latency.
//   h-pass: lane loads its A-frag (8 px/row/image) from global (2x float4 each),
//           forms 4 quantity planes in regs, 12 mfma -> private col-major H (b64).
//   v-pass: A = band, B = own H cols (b128), 8 mfma, SSIM math, wave reduce,
//           lane0 -> partial[4*block+wave].
// Band[i][k] = g[k-i-3] (halo offset -8), built via __shfl, zero outside band.

#define IMG 512
#define NPIX (16LL * 3 * 512 * 512)
#define NBLK (8 * 16 * 48)          /* 6144 blocks */
#define NPART (NBLK * 4)            /* one partial per wave: 96 KB in d_ws */
#define HP 56                       /* hbuf row pitch (shorts): 112 B = 7*16 -> aligned b128 */

typedef short v8s __attribute__((ext_vector_type(8)));   // 8 x bf16 (4 VGPRs)
typedef float v4f __attribute__((ext_vector_type(4)));   // MFMA accumulator
typedef __bf16 bf2 __attribute__((ext_vector_type(2)));
typedef float f2  __attribute__((ext_vector_type(2)));

__device__ __forceinline__ int cvtpk(float lo, float hi) {   // v_cvt_pk_bf16_f32
    f2 f; f.x = lo; f.y = hi;
    bf2 r = __builtin_convertvector(f, bf2);
    return __builtin_bit_cast(int, r);
}
__device__ __forceinline__ unsigned f2bf(float f) {
    unsigned u = __float_as_uint(f);
    return (u + 0x7FFFu + ((u >> 16) & 1u)) >> 16;
}

template <bool EDGE>
__device__ __forceinline__ void hpass(
    const float* __restrict__ p1, const float* __restrict__ p2,
    int tx0, int ty0, int lm, int quad, int ct, v8s band,
    short (*hw)[16][HP])   // this wave's private H planes [plane][col][hrow]
{
    const v4f zacc = {0.f, 0.f, 0.f, 0.f};
    #pragma unroll
    for (int rt = 0; rt < 3; ++rt) {
        const int grow = ty0 - 8 + rt * 16 + lm;        // raw pixel row
        const int gcol = tx0 - 8 + ct * 16 + quad * 8;  // raw pixel col (4-aligned)
        float4 a0, a1, b0, b1;
        if (!EDGE) {
            const float* r1 = p1 + (size_t)grow * IMG + gcol;
            const float* r2 = p2 + (size_t)grow * IMG + gcol;
            a0 = *(const float4*)r1;       a1 = *(const float4*)(r1 + 4);
            b0 = *(const float4*)r2;       b1 = *(const float4*)(r2 + 4);
        } else {
            float4 z4; z4.x = z4.y = z4.z = z4.w = 0.f;
            a0 = a1 = b0 = b1 = z4;
            if ((unsigned)grow < IMG) {
                const float* r1 = p1 + (size_t)grow * IMG;
                const float* r2 = p2 + (size_t)grow * IMG;
                if ((unsigned)gcol < IMG) {
                    a0 = *(const float4*)(r1 + gcol);
                    b0 = *(const float4*)(r2 + gcol);
                }
                if ((unsigned)(gcol + 4) < IMG) {
                    a1 = *(const float4*)(r1 + gcol + 4);
                    b1 = *(const float4*)(r2 + gcol + 4);
                }
            }
        }
        v8s A[4];
        int4 w;
        w.x = cvtpk(a0.x, a0.y); w.y = cvtpk(a0.z, a0.w);
        w.z = cvtpk(a1.x, a1.y); w.w = cvtpk(a1.z, a1.w);
        A[0] = __builtin_bit_cast(v8s, w);
        w.x = cvtpk(b0.x, b0.y); w.y = cvtpk(b0.z, b0.w);
        w.z = cvtpk(b1.x, b1.y); w.w = cvtpk(b1.z, b1.w);
        A[1] = __builtin_bit_cast(v8s, w);
        w.x = cvtpk(fmaf(a0.x, a0.x, b0.x * b0.x), fmaf(a0.y, a0.y, b0.y * b0.y));
        w.y = cvtpk(fmaf(a0.z, a0.z, b0.z * b0.z), fmaf(a0.w, a0.w, b0.w * b0.w));
        w.z = cvtpk(fmaf(a1.x, a1.x, b1.x * b1.x), fmaf(a1.y, a1.y, b1.y * b1.y));
        w.w = cvtpk(fmaf(a1.z, a1.z, b1.z * b1.z), fmaf(a1.w, a1.w, b1.w * b1.w));
        A[2] = __builtin_bit_cast(v8s, w);
        w.x = cvtpk(a0.x * b0.x, a0.y * b0.y);
        w.y = cvtpk(a0.z * b0.z, a0.w * b0.w);
        w.z = cvtpk(a1.x * b1.x, a1.y * b1.y);
        w.w = cvtpk(a1.z * b1.z, a1.w * b1.w);
        A[3] = __builtin_bit_cast(v8s, w);

        #pragma unroll
        for (int p = 0; p < 4; ++p) {
            const v4f acc = __builtin_amdgcn_mfma_f32_16x16x32_bf16(A[p], band, zacc, 0, 0, 0);
            // D C-layout: col = lm, rows rt*16 + quad*4 + reg -> col-major write.
            int2 w2;
            w2.x = cvtpk(acc[0], acc[1]);
            w2.y = cvtpk(acc[2], acc[3]);
            *(int2*)&hw[p][lm][rt * 16 + quad * 4] = w2;
        }
    }
}

__global__ __launch_bounds__(256, 5) void ssim_kernel(
    const float* __restrict__ img1,
    const float* __restrict__ img2,
    const float* __restrict__ win,
    float* __restrict__ partial)
{
    // Per-wave private H planes: [wave][plane][col][hrow-pitch]. 28672 B total.
    __shared__ __align__(16) short hbuf[4][4][16][HP];

    const int tid  = threadIdx.x;
    const int lane = tid & 63;
    const int wave = tid >> 6;
    const int lm   = lane & 15;
    const int quad = lane >> 4;

    const int bx = blockIdx.x, by = blockIdx.y, z = blockIdx.z;
    const int tx0 = bx * 64, ty0 = by * 32;

    // Band fragment via shuffle: value g[k-i-3], i = lane&15, k = quad*8+j.
    float gl = 0.f;
    if (lane < 11) gl = win[55 + lane] * rsqrtf(win[60]);
    v8s band;
    #pragma unroll
    for (int j = 0; j < 8; ++j) {
        const int t  = quad * 8 + j - lm - 3;
        const int tc = ((unsigned)t > 10u) ? 11 : t;   // lane 11 holds 0
        band[j] = (short)f2bf(__shfl(gl, tc));
    }

    const size_t zoff = (size_t)z * IMG * IMG;
    const float* p1 = img1 + zoff;
    const float* p2 = img2 + zoff;

    // ---- h-pass (wave-private, no barrier): ct = wave ----
    const bool interior = (bx > 0) & (bx < 7) & (by > 0) & (by < 15);
    if (interior) hpass<false>(p1, p2, tx0, ty0, lm, quad, wave, band, hbuf[wave]);
    else          hpass<true >(p1, p2, tx0, ty0, lm, quad, wave, band, hbuf[wave]);
    // (compiler inserts lgkmcnt wait before the dependent ds_reads below)

    // ---- v-pass: 2 row-tiles x 4 planes = 8 mfma, all from own hbuf ----
    const v4f zacc = {0.f, 0.f, 0.f, 0.f};
    const float C1c = 1e-4f;   // 0.01^2
    const float C2c = 9e-4f;   // 0.03^2
    float vsum = 0.f;
    #pragma unroll
    for (int t2 = 0; t2 < 2; ++t2) {
        const int r0v = t2 * 16;
        v4f acc[4];
        #pragma unroll
        for (int p = 0; p < 4; ++p) {
            const v8s hf = *(const v8s*)&hbuf[wave][p][lm][r0v + quad * 8];
            acc[p] = __builtin_amdgcn_mfma_f32_16x16x32_bf16(band, hf, zacc, 0, 0, 0);
        }
        #pragma unroll
        for (int r = 0; r < 4; ++r) {
            const float m1 = acc[0][r], m2 = acc[1][r];
            const float es = acc[2][r], ex = acc[3][r];
            const float m1s = m1 * m1, m2s = m2 * m2, m12 = m1 * m2;
            const float sig = es - m1s - m2s;        // sig1_sq + sig2_sq
            const float s12 = ex - m12;
            const float num = (2.f * m12 + C1c) * (2.f * s12 + C2c);
            const float den = (m1s + m2s + C1c) * (sig + C2c);
            vsum += num * __builtin_amdgcn_rcpf(den);
        }
    }

    // ---- wave reduction -> per-WAVE partial (no block barrier) ----
    #pragma unroll
    for (int off = 32; off > 0; off >>= 1)
        vsum += __shfl_down(vsum, off, 64);
    if (lane == 0) {
        const int bidx = (z * (int)gridDim.y + by) * (int)gridDim.x + bx;
        partial[bidx * 4 + wave] = vsum;
    }
}

__global__ __launch_bounds__(512) void finalize_kernel(
    const float* __restrict__ partial, float* __restrict__ out)
{
    __shared__ float red[8];
    const float4* p4 = (const float4*)partial;
    float s = 0.f;
    for (int i = threadIdx.x; i < NPART / 4; i += 512) {   // 12 iterations
        float4 t = p4[i];
        s += (t.x + t.y) + (t.z + t.w);
    }
    #pragma unroll
    for (int off = 32; off > 0; off >>= 1)
        s += __shfl_down(s, off, 64);
    if ((threadIdx.x & 63) == 0) red[threadIdx.x >> 6] = s;
    __syncthreads();
    if (threadIdx.x == 0) {
        float t = 0.f;
        #pragma unroll
        for (int i = 0; i < 8; ++i) t += red[i];
        out[0] = 1.0f - t / (float)NPIX;
    }
}

extern "C" void kernel_launch(void* const* d_in, const int* in_sizes, int n_in,
                              void* d_out, int out_size, void* d_ws, size_t ws_size,
                              hipStream_t stream) {
    const float* img1 = (const float*)d_in[0];
    const float* img2 = (const float*)d_in[1];
    const float* win  = (const float*)d_in[2];
    float* partialb = (float*)d_ws;  // NPART floats = 96 KB; every slot written each call

    dim3 grid(IMG / 64, IMG / 32, 48);
    ssim_kernel<<<grid, dim3(256), 0, stream>>>(img1, img2, win, partialb);
    finalize_kernel<<<1, dim3(512), 0, stream>>>(partialb, (float*)d_out);
}